// Round 7
// baseline (711.154 us; speedup 1.0000x reference)
//
#include <hip/hip_runtime.h>

#define NN 50000
#define EE 800000
#define DD 128
#define CC 64
#define SCAN_B 512
#define NBLK ((NN + SCAN_B - 1) / SCAN_B)   // 98
#define NBKT ((NN + 127) / 128)             // 391 buckets of 128 nodes
#define BCAP 2560                           // >> 10 sd above Poisson(2046)
#define LDA 264    // LDS A row stride in u16: 256 data + 8 pad

typedef unsigned short u16;
typedef unsigned int u32;
typedef __attribute__((ext_vector_type(8))) short short8;   // 8 bf16
typedef __attribute__((ext_vector_type(4))) float f32x4;

__device__ __forceinline__ float bf2f(u16 u) {
    union { u32 i; float f; } v; v.i = ((u32)u) << 16; return v.f;
}
__device__ __forceinline__ u16 f2bf(float f) {
    union { float f; u32 i; } v; v.f = f;
    u32 x = v.i;
    u32 r = x + 0x7fffu + ((x >> 16) & 1u);   // round-to-nearest-even
    return (u16)(r >> 16);
}

// slice-major shadow layout: (node,col) -> [(col>>5)*NN + node]*32 + (col&31)

// ---------------- bucketed CSR build ----------------

__global__ __launch_bounds__(256) void k_bucket(const int* __restrict__ src,
                                                const int* __restrict__ dst,
                                                int* __restrict__ bcnt,
                                                u32* __restrict__ bstore) {
    int e = blockIdx.x * 256 + threadIdx.x;
    if (e >= EE) return;
    int d = dst[e], s = src[e];
    int b = d >> 7;
    int pos = atomicAdd(&bcnt[b], 1);
    if (pos < BCAP) bstore[(size_t)b * BCAP + pos] = ((u32)s << 7) | (u32)(d & 127);
}

__global__ __launch_bounds__(256) void k_bdeg(const int* __restrict__ bcnt,
                                              const u32* __restrict__ bstore,
                                              int* __restrict__ deg) {
    __shared__ int hist[128];
    int b = blockIdx.x, t = threadIdx.x;
    if (t < 128) hist[t] = 0;
    __syncthreads();
    int cnt = min(bcnt[b], BCAP);
    for (int i = t; i < cnt; i += 256)
        atomicAdd(&hist[bstore[(size_t)b * BCAP + i] & 127], 1);
    __syncthreads();
    int node = b * 128 + t;
    if (t < 128 && node < NN) deg[node] = hist[t];
}

__global__ __launch_bounds__(256) void k_bfill(const int* __restrict__ bcnt,
                                               const u32* __restrict__ bstore,
                                               const int* __restrict__ row_off,
                                               int* __restrict__ csr) {
    __shared__ int ro[128];
    __shared__ int cur[128];
    int b = blockIdx.x, t = threadIdx.x;
    if (t < 128) {
        cur[t] = 0;
        int node = b * 128 + t;
        ro[t] = (node < NN) ? row_off[node] : 0;
    }
    __syncthreads();
    int cnt = min(bcnt[b], BCAP);
    for (int i = t; i < cnt; i += 256) {
        u32 v = bstore[(size_t)b * BCAP + i];
        int d7 = v & 127;
        int pos = atomicAdd(&cur[d7], 1);
        csr[ro[d7] + pos] = (int)(v >> 7);
    }
}

// ---------------- 3-phase exclusive scan over deg -> row_off, inv_deg ----------------

__global__ __launch_bounds__(512) void k_bsum(const int* __restrict__ deg,
                                              int* __restrict__ bsum) {
    __shared__ int ws[8];
    int b = blockIdx.x, t = threadIdx.x;
    int i = b * SCAN_B + t;
    int x = (i < NN) ? deg[i] : 0;
#pragma unroll
    for (int o = 1; o < 64; o <<= 1) x += __shfl_xor(x, o);
    if ((t & 63) == 0) ws[t >> 6] = x;
    __syncthreads();
    if (t == 0) {
        int s = 0;
#pragma unroll
        for (int w = 0; w < 8; ++w) s += ws[w];
        bsum[b] = s;
    }
}

__global__ __launch_bounds__(128) void k_bscan(int* __restrict__ bsum,
                                               int* __restrict__ row_off) {
    __shared__ int w0sum;
    int t = threadIdx.x;
    int v = (t < NBLK) ? bsum[t] : 0;
    int x = v;
#pragma unroll
    for (int o = 1; o < 64; o <<= 1) {
        int y = __shfl_up(x, o, 64);
        if ((t & 63) >= o) x += y;
    }
    if (t == 63) w0sum = x;
    __syncthreads();
    if (t >= 64) x += w0sum;
    if (t < NBLK) bsum[t] = x - v;       // exclusive
    if (t == NBLK - 1) row_off[NN] = x;  // total == EE
}

__global__ __launch_bounds__(512) void k_cscan(const int* __restrict__ deg,
                                               const int* __restrict__ bsum,
                                               int* __restrict__ row_off,
                                               float* __restrict__ inv_deg) {
    __shared__ int ws[8];
    int b = blockIdx.x, t = threadIdx.x;
    int i = b * SCAN_B + t;
    int v = (i < NN) ? deg[i] : 0;
    int lane = t & 63, wid = t >> 6;
    int x = v;
#pragma unroll
    for (int o = 1; o < 64; o <<= 1) {
        int y = __shfl_up(x, o, 64);
        if (lane >= o) x += y;
    }
    if (lane == 63) ws[wid] = x;
    __syncthreads();
    int woff = 0;
    for (int w = 0; w < wid; ++w) woff += ws[w];
    if (i < NN) {
        row_off[i] = bsum[b] + woff + x - v;
        inv_deg[i] = 1.0f / fmaxf((float)v, 1.0f);
    }
}

// ---------------- x -> bf16 shadow (slice-major) ----------------

__global__ __launch_bounds__(256) void k_x2bf(const float* __restrict__ x,
                                              u16* __restrict__ xb) {
    int i = (blockIdx.x * 256 + threadIdx.x) * 4;
    if (i < NN * DD) {
        float4 v = *(const float4*)(x + i);
        uint2 p;
        p.x = (u32)f2bf(v.x) | ((u32)f2bf(v.y) << 16);
        p.y = (u32)f2bf(v.z) | ((u32)f2bf(v.w) << 16);
        int node = i >> 7, col = i & 127;
        *(uint2*)(xb + ((size_t)(col >> 5) * NN + node) * 32 + (col & 31)) = p;
    }
}

// ---------------- weight pack: [Ws;Wn] (256x128) -> MFMA B-fragment order ----------------

__global__ __launch_bounds__(256) void k_wpack(const float* __restrict__ Ws,
                                               const float* __restrict__ Wn,
                                               u16* __restrict__ wpk) {
    int tid = blockIdx.x * 256 + threadIdx.x;   // 3 layers * 4096 frags
    if (tid >= 3 * 4096) return;
    int layer = tid >> 12;
    int rem = tid & 4095;
    int ks = rem >> 9;
    int nt = (rem >> 6) & 7;
    int lane = rem & 63;
    int n = nt * 16 + (lane & 15);
    int kb = ks * 32 + (lane >> 4) * 8;
    u16 o[8];
#pragma unroll
    for (int j = 0; j < 8; ++j) {
        int k = kb + j;
        float w = (k < DD) ? Ws[layer * DD * DD + k * DD + n]
                           : Wn[layer * DD * DD + (k - DD) * DD + n];
        o[j] = f2bf(w);
    }
    uint4 pk;
    pk.x = (u32)o[0] | ((u32)o[1] << 16);
    pk.y = (u32)o[2] | ((u32)o[3] << 16);
    pk.z = (u32)o[4] | ((u32)o[5] << 16);
    pk.w = (u32)o[6] | ((u32)o[7] << 16);
    *(uint4*)(wpk + (size_t)tid * 8) = pk;
}

// ---------------- mean aggregation: slice-parallel, XCD-affine ----------------
// blockIdx&3 = slice (64B of each row); 4 waves/block = 4 nodes; wave: 4 edge
// streams of 16 lanes, lane reads one u32 (2 bf16) of the slice.

__global__ __launch_bounds__(256) void k_agg(const u16* __restrict__ hb,
                                             const int* __restrict__ row_off,
                                             const int* __restrict__ csr,
                                             const float* __restrict__ inv_deg,
                                             u16* __restrict__ agb) {
    int s = blockIdx.x & 3;
    int grp = blockIdx.x >> 2;
    int wv = threadIdx.x >> 6, lane = threadIdx.x & 63;
    int node = grp * 4 + wv;
    if (node >= NN) return;
    int stream = lane >> 4, li = lane & 15;
    int beg = row_off[node], end = row_off[node + 1];
    const u32* base = (const u32*)(hb + (size_t)s * NN * 32);
    float a0 = 0.f, a1 = 0.f;
#pragma unroll 4
    for (int e = beg + stream; e < end; e += 4) {
        int sr = csr[e];
        u32 u = base[(size_t)sr * 16 + li];
        a0 += bf2f((u16)(u & 0xffffu));
        a1 += bf2f((u16)(u >> 16));
    }
    a0 += __shfl_xor(a0, 16);
    a1 += __shfl_xor(a1, 16);
    a0 += __shfl_xor(a0, 32);
    a1 += __shfl_xor(a1, 32);
    if (stream == 0) {
        float sc = inv_deg[node];
        u32 p = (u32)f2bf(a0 * sc) | ((u32)f2bf(a1 * sc) << 16);
        ((u32*)(agb + ((size_t)s * NN + node) * 32))[li] = p;
    }
}

// ---------------- MFMA fused SAGEConv layer ----------------

__global__ __launch_bounds__(256) void k_gemm(const float* __restrict__ h_in,
                                              const u16* __restrict__ hb,
                                              const u16* __restrict__ agb,
                                              const u16* __restrict__ wpk,
                                              const float* __restrict__ bias,
                                              const float* __restrict__ gmm,
                                              const float* __restrict__ bet,
                                              float* __restrict__ h_out,
                                              u16* __restrict__ hb_out,
                                              float* __restrict__ emb_out,
                                              int do_ln) {
    __shared__ u16 A[64 * LDA];
    int t = threadIdx.x;
    int b0 = blockIdx.x * 64;

    // stage A from slice-major shadows: chunk c (16B) -> slice c>>2, off (c&3)*8
#pragma unroll
    for (int j = 0; j < 4; ++j) {
        int idx = t + 256 * j;       // 1024 chunks: 64 rows x 16
        int r = idx >> 4;
        int c = idx & 15;
        int node = b0 + r;
        uint4 v = make_uint4(0, 0, 0, 0), w = make_uint4(0, 0, 0, 0);
        if (node < NN) {
            size_t off = ((size_t)(c >> 2) * NN + node) * 32 + (c & 3) * 8;
            v = *(const uint4*)(hb + off);
            w = *(const uint4*)(agb + off);
        }
        *(uint4*)&A[r * LDA + c * 8] = v;
        *(uint4*)&A[r * LDA + 128 + c * 8] = w;
    }
    __syncthreads();

    int wv = t >> 6, lane = t & 63;
    int m = lane & 15, q = lane >> 4;

    f32x4 acc[8];
#pragma unroll
    for (int nt = 0; nt < 8; ++nt) acc[nt] = (f32x4)(0.f);

    const u16* Arow = &A[(wv * 16 + m) * LDA + q * 8];
    const short8* wp = (const short8*)wpk;
#pragma unroll
    for (int ks = 0; ks < 8; ++ks) {
        short8 af = *(const short8*)(Arow + ks * 32);
        const short8* bp = wp + (ks * 8) * 64 + lane;
#pragma unroll
        for (int nt = 0; nt < 8; ++nt) {
            short8 bf = bp[nt * 64];
            acc[nt] = __builtin_amdgcn_mfma_f32_16x16x32_bf16(af, bf, acc[nt], 0, 0, 0);
        }
    }

    float bcol[8], gcol[8], ecol[8];
#pragma unroll
    for (int nt = 0; nt < 8; ++nt) {
        bcol[nt] = bias[nt * 16 + m];
        if (do_ln) { gcol[nt] = gmm[nt * 16 + m]; ecol[nt] = bet[nt * 16 + m]; }
    }

#pragma unroll
    for (int j = 0; j < 4; ++j) {
        int node = b0 + wv * 16 + q * 4 + j;
        bool ok = node < NN;
        const float* hr = h_in + (size_t)node * DD;
        float v[8];
        float s = 0.f, qq = 0.f;
#pragma unroll
        for (int nt = 0; nt < 8; ++nt) {
            float x = acc[nt][j] + bcol[nt];
            if (ok) x += hr[nt * 16 + m];        // fp32 residual
            if (do_ln) {
                x = fmaxf(x, 0.f);
                s += x; qq += x * x;
            }
            v[nt] = x;
        }
        if (do_ln) {
#pragma unroll
            for (int o = 1; o < 16; o <<= 1) {
                s += __shfl_xor(s, o);
                qq += __shfl_xor(qq, o);
            }
            float mu = s * (1.0f / 128.0f);
            float var = fmaxf(qq * (1.0f / 128.0f) - mu * mu, 0.f);
            float rs = rsqrtf(var + 1e-5f);
#pragma unroll
            for (int nt = 0; nt < 8; ++nt)
                v[nt] = gcol[nt] * (v[nt] - mu) * rs + ecol[nt];
        }
        if (ok) {
            float* orow = h_out + (size_t)node * DD;
#pragma unroll
            for (int nt = 0; nt < 8; ++nt) orow[nt * 16 + m] = v[nt];
            if (hb_out) {
#pragma unroll
                for (int nt = 0; nt < 8; ++nt)
                    hb_out[((size_t)(nt >> 1) * NN + node) * 32 + (nt & 1) * 16 + m] = f2bf(v[nt]);
            }
            if (emb_out) {
                float* erow = emb_out + (size_t)node * DD;
#pragma unroll
                for (int nt = 0; nt < 8; ++nt) erow[nt * 16 + m] = v[nt];
            }
        }
    }
}

// ---------------- output head: logits = h @ Wout + bout (fp32 vector) ----------------

__device__ __forceinline__ void stage_tile(const float* __restrict__ g, int b0,
                                           float* __restrict__ tile, int t) {
#pragma unroll
    for (int j = 0; j < 8; ++j) {
        int idx = t + 256 * j;
        int r = idx >> 5;
        int c = idx & 31;
        int node = b0 + r;
        float4 f = make_float4(0.f, 0.f, 0.f, 0.f);
        if (node < NN) f = *(const float4*)(g + (size_t)node * DD + c * 4);
        *(float4*)&tile[r * DD + c * 4] = f;
    }
}

__global__ __launch_bounds__(256) void k_logits(const float* __restrict__ h,
                                                const float* __restrict__ Wo,
                                                const float* __restrict__ bo,
                                                float* __restrict__ out) {
    __shared__ float tile[64 * DD];
    int t = threadIdx.x;
    int b0 = blockIdx.x * 64;
    int cg = t & 15;
    int ng = t >> 4;
    stage_tile(h, b0, tile, t);
    __syncthreads();
    float acc[4][4];
#pragma unroll
    for (int i = 0; i < 4; ++i)
#pragma unroll
        for (int j = 0; j < 4; ++j) acc[i][j] = 0.f;
    for (int k = 0; k < DD; k += 4) {
        float4 w0 = *(const float4*)(Wo + (k + 0) * CC + cg * 4);
        float4 w1 = *(const float4*)(Wo + (k + 1) * CC + cg * 4);
        float4 w2 = *(const float4*)(Wo + (k + 2) * CC + cg * 4);
        float4 w3 = *(const float4*)(Wo + (k + 3) * CC + cg * 4);
#pragma unroll
        for (int i = 0; i < 4; ++i) {
            float4 hv = *(const float4*)&tile[(ng * 4 + i) * DD + k];
            acc[i][0] = fmaf(hv.x, w0.x, fmaf(hv.y, w1.x, fmaf(hv.z, w2.x, fmaf(hv.w, w3.x, acc[i][0]))));
            acc[i][1] = fmaf(hv.x, w0.y, fmaf(hv.y, w1.y, fmaf(hv.z, w2.y, fmaf(hv.w, w3.y, acc[i][1]))));
            acc[i][2] = fmaf(hv.x, w0.z, fmaf(hv.y, w1.z, fmaf(hv.z, w2.z, fmaf(hv.w, w3.z, acc[i][2]))));
            acc[i][3] = fmaf(hv.x, w0.w, fmaf(hv.y, w1.w, fmaf(hv.z, w2.w, fmaf(hv.w, w3.w, acc[i][3]))));
        }
    }
    float4 b4 = *(const float4*)(bo + cg * 4);
#pragma unroll
    for (int i = 0; i < 4; ++i) {
        int node = b0 + ng * 4 + i;
        if (node < NN) {
            *(float4*)(out + (size_t)node * CC + cg * 4) =
                make_float4(acc[i][0] + b4.x, acc[i][1] + b4.y,
                            acc[i][2] + b4.z, acc[i][3] + b4.w);
        }
    }
}

// ---------------- launch ----------------

extern "C" void kernel_launch(void* const* d_in, const int* in_sizes, int n_in,
                              void* d_out, int out_size, void* d_ws, size_t ws_size,
                              hipStream_t stream) {
    const float* x  = (const float*)d_in[0];
    const int* src  = (const int*)d_in[1];
    const int* dst  = (const int*)d_in[2];
    const float* Ws = (const float*)d_in[3];
    const float* Wn = (const float*)d_in[4];
    const float* bc = (const float*)d_in[5];
    const float* gm = (const float*)d_in[6];
    const float* bt = (const float*)d_in[7];
    const float* Wo = (const float*)d_in[8];
    const float* bo = (const float*)d_in[9];
    float* out = (float*)d_out;   // fp32: logits [NN*CC] then embedding [NN*DD]

    char* p = (char*)d_ws;
    auto alloc = [&](size_t bytes) { void* r = (void*)p; p += (bytes + 255) & ~(size_t)255; return r; };
    float* h0    = (float*)alloc((size_t)NN * DD * 4);
    float* h1    = (float*)alloc((size_t)NN * DD * 4);
    u16* xb      = (u16*)alloc((size_t)NN * DD * 2);
    u16* hb0     = (u16*)alloc((size_t)NN * DD * 2);
    u16* hb1     = (u16*)alloc((size_t)NN * DD * 2);
    u16* agb     = (u16*)alloc((size_t)NN * DD * 2);
    u16* wpk     = (u16*)alloc((size_t)3 * 4096 * 8 * 2);
    float* invd  = (float*)alloc(NN * 4);
    int* deg     = (int*)alloc(NN * 4);
    int* row_off = (int*)alloc((NN + 1) * 4);
    int* bsum    = (int*)alloc(NBLK * 4);
    int* csr     = (int*)alloc(EE * 4);
    int* bcnt    = (int*)alloc(NBKT * 4);
    u32* bstore  = (u32*)alloc((size_t)NBKT * BCAP * 4);

    hipMemsetAsync(bcnt, 0, NBKT * 4, stream);

    k_bucket<<<(EE + 255) / 256, 256, 0, stream>>>(src, dst, bcnt, bstore);
    k_bdeg<<<NBKT, 256, 0, stream>>>(bcnt, bstore, deg);
    k_bsum<<<NBLK, SCAN_B, 0, stream>>>(deg, bsum);
    k_bscan<<<1, 128, 0, stream>>>(bsum, row_off);
    k_cscan<<<NBLK, SCAN_B, 0, stream>>>(deg, bsum, row_off, invd);
    k_bfill<<<NBKT, 256, 0, stream>>>(bcnt, bstore, row_off, csr);
    k_x2bf<<<(NN * DD / 4 + 255) / 256, 256, 0, stream>>>(x, xb);
    k_wpack<<<(3 * 4096 + 255) / 256, 256, 0, stream>>>(Ws, Wn, wpk);

    const float* hin = x;
    const u16* hbin = xb;
    float* houts[3] = {h0, h1, h0};
    u16* hbouts[3] = {hb0, hb1, (u16*)nullptr};
    int aggrid = ((NN + 3) / 4) * 4;   // (node-group) x 4 slices
    for (int l = 0; l < 3; ++l) {
        k_agg<<<aggrid, 256, 0, stream>>>(hbin, row_off, csr, invd, agb);
        k_gemm<<<(NN + 63) / 64, 256, 0, stream>>>(
            hin, hbin, agb, wpk + (size_t)l * 4096 * 8,
            bc + l * DD,
            (l < 2) ? gm + l * DD : (const float*)nullptr,
            (l < 2) ? bt + l * DD : (const float*)nullptr,
            houts[l], hbouts[l],
            (l == 2) ? out + (size_t)NN * CC : (float*)nullptr,
            (l < 2) ? 1 : 0);
        hin = houts[l];
        hbin = hbouts[l];
    }
    k_logits<<<(NN + 63) / 64, 256, 0, stream>>>(h0, Wo, bo, out);
}

// Round 8
// 501.611 us; speedup vs baseline: 1.4177x; 1.4177x over previous
//
#include <hip/hip_runtime.h>

#define NN 50000
#define EE 800000
#define DD 128
#define CC 64
#define SCAN_B 512
#define NBLK ((NN + SCAN_B - 1) / SCAN_B)   // 98
#define LDA 264    // LDS A row stride in u16: 256 data + 8 pad

typedef unsigned short u16;
typedef unsigned int u32;
typedef __attribute__((ext_vector_type(8))) short short8;   // 8 bf16
typedef __attribute__((ext_vector_type(4))) float f32x4;

__device__ __forceinline__ float bf2f(u16 u) {
    union { u32 i; float f; } v; v.i = ((u32)u) << 16; return v.f;
}
__device__ __forceinline__ u16 f2bf(float f) {
    union { float f; u32 i; } v; v.f = f;
    u32 x = v.i;
    u32 r = x + 0x7fffu + ((x >> 16) & 1u);   // round-to-nearest-even
    return (u16)(r >> 16);
}

// slice-major shadow layout: (node,col) -> [(col>>5)*NN + node]*32 + (col&31)

// ---------------- CSR build (round-6 proven path) ----------------

__global__ __launch_bounds__(256) void k_degree(const int* __restrict__ dst,
                                                int* __restrict__ deg) {
    int e = blockIdx.x * 256 + threadIdx.x;
    if (e < EE) atomicAdd(&deg[dst[e]], 1);
}

__global__ __launch_bounds__(512) void k_bsum(const int* __restrict__ deg,
                                              int* __restrict__ bsum) {
    __shared__ int ws[8];
    int b = blockIdx.x, t = threadIdx.x;
    int i = b * SCAN_B + t;
    int x = (i < NN) ? deg[i] : 0;
#pragma unroll
    for (int o = 1; o < 64; o <<= 1) x += __shfl_xor(x, o);
    if ((t & 63) == 0) ws[t >> 6] = x;
    __syncthreads();
    if (t == 0) {
        int s = 0;
#pragma unroll
        for (int w = 0; w < 8; ++w) s += ws[w];
        bsum[b] = s;
    }
}

__global__ __launch_bounds__(128) void k_bscan(int* __restrict__ bsum,
                                               int* __restrict__ row_off) {
    __shared__ int w0sum;
    int t = threadIdx.x;
    int v = (t < NBLK) ? bsum[t] : 0;
    int x = v;
#pragma unroll
    for (int o = 1; o < 64; o <<= 1) {
        int y = __shfl_up(x, o, 64);
        if ((t & 63) >= o) x += y;
    }
    if (t == 63) w0sum = x;
    __syncthreads();
    if (t >= 64) x += w0sum;
    if (t < NBLK) bsum[t] = x - v;       // exclusive
    if (t == NBLK - 1) row_off[NN] = x;  // total == EE
}

__global__ __launch_bounds__(512) void k_cscan(const int* __restrict__ deg,
                                               const int* __restrict__ bsum,
                                               int* __restrict__ row_off,
                                               float* __restrict__ inv_deg) {
    __shared__ int ws[8];
    int b = blockIdx.x, t = threadIdx.x;
    int i = b * SCAN_B + t;
    int v = (i < NN) ? deg[i] : 0;
    int lane = t & 63, wid = t >> 6;
    int x = v;
#pragma unroll
    for (int o = 1; o < 64; o <<= 1) {
        int y = __shfl_up(x, o, 64);
        if (lane >= o) x += y;
    }
    if (lane == 63) ws[wid] = x;
    __syncthreads();
    int woff = 0;
    for (int w = 0; w < wid; ++w) woff += ws[w];
    if (i < NN) {
        row_off[i] = bsum[b] + woff + x - v;
        inv_deg[i] = 1.0f / fmaxf((float)v, 1.0f);
    }
}

__global__ __launch_bounds__(256) void k_fill(const int* __restrict__ src,
                                              const int* __restrict__ dst,
                                              const int* __restrict__ row_off,
                                              int* __restrict__ cursor,
                                              int* __restrict__ csr) {
    int e = blockIdx.x * 256 + threadIdx.x;
    if (e < EE) {
        int d = dst[e];
        int pos = atomicAdd(&cursor[d], 1);
        csr[row_off[d] + pos] = src[e];
    }
}

// ---------------- x -> bf16 shadow (slice-major) ----------------

__global__ __launch_bounds__(256) void k_x2bf(const float* __restrict__ x,
                                              u16* __restrict__ xb) {
    int i = (blockIdx.x * 256 + threadIdx.x) * 4;
    if (i < NN * DD) {
        float4 v = *(const float4*)(x + i);
        uint2 p;
        p.x = (u32)f2bf(v.x) | ((u32)f2bf(v.y) << 16);
        p.y = (u32)f2bf(v.z) | ((u32)f2bf(v.w) << 16);
        int node = i >> 7, col = i & 127;
        *(uint2*)(xb + ((size_t)(col >> 5) * NN + node) * 32 + (col & 31)) = p;
    }
}

// ---------------- weight pack: [Ws;Wn] (256x128) -> MFMA B-fragment order ----------------

__global__ __launch_bounds__(256) void k_wpack(const float* __restrict__ Ws,
                                               const float* __restrict__ Wn,
                                               u16* __restrict__ wpk) {
    int tid = blockIdx.x * 256 + threadIdx.x;   // 3 layers * 4096 frags
    if (tid >= 3 * 4096) return;
    int layer = tid >> 12;
    int rem = tid & 4095;
    int ks = rem >> 9;
    int nt = (rem >> 6) & 7;
    int lane = rem & 63;
    int n = nt * 16 + (lane & 15);
    int kb = ks * 32 + (lane >> 4) * 8;
    u16 o[8];
#pragma unroll
    for (int j = 0; j < 8; ++j) {
        int k = kb + j;
        float w = (k < DD) ? Ws[layer * DD * DD + k * DD + n]
                           : Wn[layer * DD * DD + (k - DD) * DD + n];
        o[j] = f2bf(w);
    }
    uint4 pk;
    pk.x = (u32)o[0] | ((u32)o[1] << 16);
    pk.y = (u32)o[2] | ((u32)o[3] << 16);
    pk.z = (u32)o[4] | ((u32)o[5] << 16);
    pk.w = (u32)o[6] | ((u32)o[7] << 16);
    *(uint4*)(wpk + (size_t)tid * 8) = pk;
}

// ---------------- mean aggregation: slice-parallel, XCD-affine ----------------
// blockIdx&3 = slice (64B of each row); 4 waves/block = 4 nodes; wave: 4 edge
// streams of 16 lanes, lane reads one u32 (2 bf16) of the slice.

__global__ __launch_bounds__(256) void k_agg(const u16* __restrict__ hb,
                                             const int* __restrict__ row_off,
                                             const int* __restrict__ csr,
                                             const float* __restrict__ inv_deg,
                                             u16* __restrict__ agb) {
    int s = blockIdx.x & 3;
    int grp = blockIdx.x >> 2;
    int wv = threadIdx.x >> 6, lane = threadIdx.x & 63;
    int node = grp * 4 + wv;
    if (node >= NN) return;
    int stream = lane >> 4, li = lane & 15;
    int beg = row_off[node], end = row_off[node + 1];
    const u32* base = (const u32*)(hb + (size_t)s * NN * 32);
    float a0 = 0.f, a1 = 0.f;
#pragma unroll 4
    for (int e = beg + stream; e < end; e += 4) {
        int sr = csr[e];
        u32 u = base[(size_t)sr * 16 + li];
        a0 += bf2f((u16)(u & 0xffffu));
        a1 += bf2f((u16)(u >> 16));
    }
    a0 += __shfl_xor(a0, 16);
    a1 += __shfl_xor(a1, 16);
    a0 += __shfl_xor(a0, 32);
    a1 += __shfl_xor(a1, 32);
    if (stream == 0) {
        float sc = inv_deg[node];
        u32 p = (u32)f2bf(a0 * sc) | ((u32)f2bf(a1 * sc) << 16);
        ((u32*)(agb + ((size_t)s * NN + node) * 32))[li] = p;
    }
}

// ---------------- MFMA fused SAGEConv layer ----------------

__global__ __launch_bounds__(256) void k_gemm(const float* __restrict__ h_in,
                                              const u16* __restrict__ hb,
                                              const u16* __restrict__ agb,
                                              const u16* __restrict__ wpk,
                                              const float* __restrict__ bias,
                                              const float* __restrict__ gmm,
                                              const float* __restrict__ bet,
                                              float* __restrict__ h_out,
                                              u16* __restrict__ hb_out,
                                              float* __restrict__ emb_out,
                                              int do_ln) {
    __shared__ u16 A[64 * LDA];
    int t = threadIdx.x;
    int b0 = blockIdx.x * 64;

    // stage A from slice-major shadows: chunk c (16B) -> slice c>>2, off (c&3)*8
#pragma unroll
    for (int j = 0; j < 4; ++j) {
        int idx = t + 256 * j;       // 1024 chunks: 64 rows x 16
        int r = idx >> 4;
        int c = idx & 15;
        int node = b0 + r;
        uint4 v = make_uint4(0, 0, 0, 0), w = make_uint4(0, 0, 0, 0);
        if (node < NN) {
            size_t off = ((size_t)(c >> 2) * NN + node) * 32 + (c & 3) * 8;
            v = *(const uint4*)(hb + off);
            w = *(const uint4*)(agb + off);
        }
        *(uint4*)&A[r * LDA + c * 8] = v;
        *(uint4*)&A[r * LDA + 128 + c * 8] = w;
    }
    __syncthreads();

    int wv = t >> 6, lane = t & 63;
    int m = lane & 15, q = lane >> 4;

    f32x4 acc[8];
#pragma unroll
    for (int nt = 0; nt < 8; ++nt) acc[nt] = (f32x4)(0.f);

    const u16* Arow = &A[(wv * 16 + m) * LDA + q * 8];
    const short8* wp = (const short8*)wpk;
#pragma unroll
    for (int ks = 0; ks < 8; ++ks) {
        short8 af = *(const short8*)(Arow + ks * 32);
        const short8* bp = wp + (ks * 8) * 64 + lane;
#pragma unroll
        for (int nt = 0; nt < 8; ++nt) {
            short8 bf = bp[nt * 64];
            acc[nt] = __builtin_amdgcn_mfma_f32_16x16x32_bf16(af, bf, acc[nt], 0, 0, 0);
        }
    }

    float bcol[8], gcol[8], ecol[8];
#pragma unroll
    for (int nt = 0; nt < 8; ++nt) {
        bcol[nt] = bias[nt * 16 + m];
        if (do_ln) { gcol[nt] = gmm[nt * 16 + m]; ecol[nt] = bet[nt * 16 + m]; }
    }

#pragma unroll
    for (int j = 0; j < 4; ++j) {
        int node = b0 + wv * 16 + q * 4 + j;
        bool ok = node < NN;
        const float* hr = h_in + (size_t)node * DD;
        float v[8];
        float s = 0.f, qq = 0.f;
#pragma unroll
        for (int nt = 0; nt < 8; ++nt) {
            float x = acc[nt][j] + bcol[nt];
            if (ok) x += hr[nt * 16 + m];        // fp32 residual
            if (do_ln) {
                x = fmaxf(x, 0.f);
                s += x; qq += x * x;
            }
            v[nt] = x;
        }
        if (do_ln) {
#pragma unroll
            for (int o = 1; o < 16; o <<= 1) {
                s += __shfl_xor(s, o);
                qq += __shfl_xor(qq, o);
            }
            float mu = s * (1.0f / 128.0f);
            float var = fmaxf(qq * (1.0f / 128.0f) - mu * mu, 0.f);
            float rs = rsqrtf(var + 1e-5f);
#pragma unroll
            for (int nt = 0; nt < 8; ++nt)
                v[nt] = gcol[nt] * (v[nt] - mu) * rs + ecol[nt];
        }
        if (ok) {
            float* orow = h_out + (size_t)node * DD;
#pragma unroll
            for (int nt = 0; nt < 8; ++nt) orow[nt * 16 + m] = v[nt];
            if (hb_out) {
#pragma unroll
                for (int nt = 0; nt < 8; ++nt)
                    hb_out[((size_t)(nt >> 1) * NN + node) * 32 + (nt & 1) * 16 + m] = f2bf(v[nt]);
            }
            if (emb_out) {
                float* erow = emb_out + (size_t)node * DD;
#pragma unroll
                for (int nt = 0; nt < 8; ++nt) erow[nt * 16 + m] = v[nt];
            }
        }
    }
}

// ---------------- output head: logits = h @ Wout + bout (fp32 vector) ----------------

__device__ __forceinline__ void stage_tile(const float* __restrict__ g, int b0,
                                           float* __restrict__ tile, int t) {
#pragma unroll
    for (int j = 0; j < 8; ++j) {
        int idx = t + 256 * j;
        int r = idx >> 5;
        int c = idx & 31;
        int node = b0 + r;
        float4 f = make_float4(0.f, 0.f, 0.f, 0.f);
        if (node < NN) f = *(const float4*)(g + (size_t)node * DD + c * 4);
        *(float4*)&tile[r * DD + c * 4] = f;
    }
}

__global__ __launch_bounds__(256) void k_logits(const float* __restrict__ h,
                                                const float* __restrict__ Wo,
                                                const float* __restrict__ bo,
                                                float* __restrict__ out) {
    __shared__ float tile[64 * DD];
    int t = threadIdx.x;
    int b0 = blockIdx.x * 64;
    int cg = t & 15;
    int ng = t >> 4;
    stage_tile(h, b0, tile, t);
    __syncthreads();
    float acc[4][4];
#pragma unroll
    for (int i = 0; i < 4; ++i)
#pragma unroll
        for (int j = 0; j < 4; ++j) acc[i][j] = 0.f;
    for (int k = 0; k < DD; k += 4) {
        float4 w0 = *(const float4*)(Wo + (k + 0) * CC + cg * 4);
        float4 w1 = *(const float4*)(Wo + (k + 1) * CC + cg * 4);
        float4 w2 = *(const float4*)(Wo + (k + 2) * CC + cg * 4);
        float4 w3 = *(const float4*)(Wo + (k + 3) * CC + cg * 4);
#pragma unroll
        for (int i = 0; i < 4; ++i) {
            float4 hv = *(const float4*)&tile[(ng * 4 + i) * DD + k];
            acc[i][0] = fmaf(hv.x, w0.x, fmaf(hv.y, w1.x, fmaf(hv.z, w2.x, fmaf(hv.w, w3.x, acc[i][0]))));
            acc[i][1] = fmaf(hv.x, w0.y, fmaf(hv.y, w1.y, fmaf(hv.z, w2.y, fmaf(hv.w, w3.y, acc[i][1]))));
            acc[i][2] = fmaf(hv.x, w0.z, fmaf(hv.y, w1.z, fmaf(hv.z, w2.z, fmaf(hv.w, w3.z, acc[i][2]))));
            acc[i][3] = fmaf(hv.x, w0.w, fmaf(hv.y, w1.w, fmaf(hv.z, w2.w, fmaf(hv.w, w3.w, acc[i][3]))));
        }
    }
    float4 b4 = *(const float4*)(bo + cg * 4);
#pragma unroll
    for (int i = 0; i < 4; ++i) {
        int node = b0 + ng * 4 + i;
        if (node < NN) {
            *(float4*)(out + (size_t)node * CC + cg * 4) =
                make_float4(acc[i][0] + b4.x, acc[i][1] + b4.y,
                            acc[i][2] + b4.z, acc[i][3] + b4.w);
        }
    }
}

// ---------------- launch ----------------

extern "C" void kernel_launch(void* const* d_in, const int* in_sizes, int n_in,
                              void* d_out, int out_size, void* d_ws, size_t ws_size,
                              hipStream_t stream) {
    const float* x  = (const float*)d_in[0];
    const int* src  = (const int*)d_in[1];
    const int* dst  = (const int*)d_in[2];
    const float* Ws = (const float*)d_in[3];
    const float* Wn = (const float*)d_in[4];
    const float* bc = (const float*)d_in[5];
    const float* gm = (const float*)d_in[6];
    const float* bt = (const float*)d_in[7];
    const float* Wo = (const float*)d_in[8];
    const float* bo = (const float*)d_in[9];
    float* out = (float*)d_out;   // fp32: logits [NN*CC] then embedding [NN*DD]

    char* p = (char*)d_ws;
    auto alloc = [&](size_t bytes) { void* r = (void*)p; p += (bytes + 255) & ~(size_t)255; return r; };
    float* h0    = (float*)alloc((size_t)NN * DD * 4);
    float* h1    = (float*)alloc((size_t)NN * DD * 4);
    u16* xb      = (u16*)alloc((size_t)NN * DD * 2);
    u16* hb0     = (u16*)alloc((size_t)NN * DD * 2);
    u16* hb1     = (u16*)alloc((size_t)NN * DD * 2);
    u16* agb     = (u16*)alloc((size_t)NN * DD * 2);
    u16* wpk     = (u16*)alloc((size_t)3 * 4096 * 8 * 2);
    float* invd  = (float*)alloc(NN * 4);
    int* deg     = (int*)alloc(NN * 4);
    int* row_off = (int*)alloc((NN + 1) * 4);
    int* cursor  = (int*)alloc(NN * 4);
    int* bsum    = (int*)alloc(NBLK * 4);
    int* csr     = (int*)alloc(EE * 4);

    hipMemsetAsync(deg, 0, NN * 4, stream);
    hipMemsetAsync(cursor, 0, NN * 4, stream);

    k_degree<<<(EE + 255) / 256, 256, 0, stream>>>(dst, deg);
    k_bsum<<<NBLK, SCAN_B, 0, stream>>>(deg, bsum);
    k_bscan<<<1, 128, 0, stream>>>(bsum, row_off);
    k_cscan<<<NBLK, SCAN_B, 0, stream>>>(deg, bsum, row_off, invd);
    k_fill<<<(EE + 255) / 256, 256, 0, stream>>>(src, dst, row_off, cursor, csr);
    k_x2bf<<<(NN * DD / 4 + 255) / 256, 256, 0, stream>>>(x, xb);
    k_wpack<<<(3 * 4096 + 255) / 256, 256, 0, stream>>>(Ws, Wn, wpk);

    const float* hin = x;
    const u16* hbin = xb;
    float* houts[3] = {h0, h1, h0};
    u16* hbouts[3] = {hb0, hb1, (u16*)nullptr};
    int aggrid = ((NN + 3) / 4) * 4;   // (node-group) x 4 slices
    for (int l = 0; l < 3; ++l) {
        k_agg<<<aggrid, 256, 0, stream>>>(hbin, row_off, csr, invd, agb);
        k_gemm<<<(NN + 63) / 64, 256, 0, stream>>>(
            hin, hbin, agb, wpk + (size_t)l * 4096 * 8,
            bc + l * DD,
            (l < 2) ? gm + l * DD : (const float*)nullptr,
            (l < 2) ? bt + l * DD : (const float*)nullptr,
            houts[l], hbouts[l],
            (l == 2) ? out + (size_t)NN * CC : (float*)nullptr,
            (l < 2) ? 1 : 0);
        hin = houts[l];
        hbin = hbouts[l];
    }
    k_logits<<<(NN + 63) / 64, 256, 0, stream>>>(h0, Wo, bo, out);
}

// Round 9
// 383.389 us; speedup vs baseline: 1.8549x; 1.3084x over previous
//
#include <hip/hip_runtime.h>

#define NN 50000
#define EE 800000
#define DD 128
#define CC 64
#define SCAN_B 512
#define NBLK ((NN + SCAN_B - 1) / SCAN_B)   // 98
#define LDA 264    // LDS A row stride in u16: 256 data + 8 pad

typedef unsigned short u16;
typedef unsigned int u32;
typedef __attribute__((ext_vector_type(8))) short short8;   // 8 bf16
typedef __attribute__((ext_vector_type(4))) float f32x4;

__device__ __forceinline__ float bf2f(u16 u) {
    union { u32 i; float f; } v; v.i = ((u32)u) << 16; return v.f;
}
__device__ __forceinline__ u16 f2bf(float f) {
    union { float f; u32 i; } v; v.f = f;
    u32 x = v.i;
    u32 r = x + 0x7fffu + ((x >> 16) & 1u);   // round-to-nearest-even
    return (u16)(r >> 16);
}

// ---------------- CSR build (round-6 proven path) ----------------

__global__ __launch_bounds__(256) void k_degree(const int* __restrict__ dst,
                                                int* __restrict__ deg) {
    int e = blockIdx.x * 256 + threadIdx.x;
    if (e < EE) atomicAdd(&deg[dst[e]], 1);
}

__global__ __launch_bounds__(512) void k_bsum(const int* __restrict__ deg,
                                              int* __restrict__ bsum) {
    __shared__ int ws[8];
    int b = blockIdx.x, t = threadIdx.x;
    int i = b * SCAN_B + t;
    int x = (i < NN) ? deg[i] : 0;
#pragma unroll
    for (int o = 1; o < 64; o <<= 1) x += __shfl_xor(x, o);
    if ((t & 63) == 0) ws[t >> 6] = x;
    __syncthreads();
    if (t == 0) {
        int s = 0;
#pragma unroll
        for (int w = 0; w < 8; ++w) s += ws[w];
        bsum[b] = s;
    }
}

__global__ __launch_bounds__(128) void k_bscan(int* __restrict__ bsum,
                                               int* __restrict__ row_off) {
    __shared__ int w0sum;
    int t = threadIdx.x;
    int v = (t < NBLK) ? bsum[t] : 0;
    int x = v;
#pragma unroll
    for (int o = 1; o < 64; o <<= 1) {
        int y = __shfl_up(x, o, 64);
        if ((t & 63) >= o) x += y;
    }
    if (t == 63) w0sum = x;
    __syncthreads();
    if (t >= 64) x += w0sum;
    if (t < NBLK) bsum[t] = x - v;       // exclusive
    if (t == NBLK - 1) row_off[NN] = x;  // total == EE
}

__global__ __launch_bounds__(512) void k_cscan(const int* __restrict__ deg,
                                               const int* __restrict__ bsum,
                                               int* __restrict__ row_off,
                                               float* __restrict__ inv_deg) {
    __shared__ int ws[8];
    int b = blockIdx.x, t = threadIdx.x;
    int i = b * SCAN_B + t;
    int v = (i < NN) ? deg[i] : 0;
    int lane = t & 63, wid = t >> 6;
    int x = v;
#pragma unroll
    for (int o = 1; o < 64; o <<= 1) {
        int y = __shfl_up(x, o, 64);
        if (lane >= o) x += y;
    }
    if (lane == 63) ws[wid] = x;
    __syncthreads();
    int woff = 0;
    for (int w = 0; w < wid; ++w) woff += ws[w];
    if (i < NN) {
        row_off[i] = bsum[b] + woff + x - v;
        inv_deg[i] = 1.0f / fmaxf((float)v, 1.0f);
    }
}

__global__ __launch_bounds__(256) void k_fill(const int* __restrict__ src,
                                              const int* __restrict__ dst,
                                              const int* __restrict__ row_off,
                                              int* __restrict__ cursor,
                                              int* __restrict__ csr) {
    int e = blockIdx.x * 256 + threadIdx.x;
    if (e < EE) {
        int d = dst[e];
        int pos = atomicAdd(&cursor[d], 1);
        csr[row_off[d] + pos] = src[e];
    }
}

// ---------------- x -> bf16 shadow (node-major) ----------------

__global__ __launch_bounds__(256) void k_x2bf(const float* __restrict__ x,
                                              u16* __restrict__ xb) {
    int i = (blockIdx.x * 256 + threadIdx.x) * 4;
    if (i < NN * DD) {
        float4 v = *(const float4*)(x + i);
        uint2 p;
        p.x = (u32)f2bf(v.x) | ((u32)f2bf(v.y) << 16);
        p.y = (u32)f2bf(v.z) | ((u32)f2bf(v.w) << 16);
        *(uint2*)(xb + i) = p;
    }
}

// ---------------- weight pack: [Ws;Wn] (256x128) -> MFMA B-fragment order ----------------

__global__ __launch_bounds__(256) void k_wpack(const float* __restrict__ Ws,
                                               const float* __restrict__ Wn,
                                               u16* __restrict__ wpk) {
    int tid = blockIdx.x * 256 + threadIdx.x;   // 3 layers * 4096 frags
    if (tid >= 3 * 4096) return;
    int layer = tid >> 12;
    int rem = tid & 4095;
    int ks = rem >> 9;
    int nt = (rem >> 6) & 7;
    int lane = rem & 63;
    int n = nt * 16 + (lane & 15);
    int kb = ks * 32 + (lane >> 4) * 8;
    u16 o[8];
#pragma unroll
    for (int j = 0; j < 8; ++j) {
        int k = kb + j;
        float w = (k < DD) ? Ws[layer * DD * DD + k * DD + n]
                           : Wn[layer * DD * DD + (k - DD) * DD + n];
        o[j] = f2bf(w);
    }
    uint4 pk;
    pk.x = (u32)o[0] | ((u32)o[1] << 16);
    pk.y = (u32)o[2] | ((u32)o[3] << 16);
    pk.z = (u32)o[4] | ((u32)o[5] << 16);
    pk.w = (u32)o[6] | ((u32)o[7] << 16);
    *(uint4*)(wpk + (size_t)tid * 8) = pk;
}

// ---------------- mean aggregation: one wave per node, 4 edge streams x uint4 ----------------
// stream = lane>>4 (4 edges in flight); li = lane&15 covers the 256B row in 16B chunks.

__global__ __launch_bounds__(256) void k_agg(const u16* __restrict__ hb,
                                             const int* __restrict__ row_off,
                                             const int* __restrict__ csr,
                                             const float* __restrict__ inv_deg,
                                             u16* __restrict__ agb) {
    int wave = blockIdx.x * 4 + (threadIdx.x >> 6);
    int lane = threadIdx.x & 63;
    if (wave >= NN) return;
    int stream = lane >> 4, li = lane & 15;
    int beg = row_off[wave], end = row_off[wave + 1];
    float a0 = 0.f, a1 = 0.f, a2 = 0.f, a3 = 0.f;
    float a4 = 0.f, a5 = 0.f, a6 = 0.f, a7 = 0.f;
#pragma unroll 4
    for (int e = beg + stream; e < end; e += 4) {
        int s = csr[e];
        uint4 u = *(const uint4*)(hb + (size_t)s * DD + li * 8);
        a0 += bf2f((u16)(u.x & 0xffffu));
        a1 += bf2f((u16)(u.x >> 16));
        a2 += bf2f((u16)(u.y & 0xffffu));
        a3 += bf2f((u16)(u.y >> 16));
        a4 += bf2f((u16)(u.z & 0xffffu));
        a5 += bf2f((u16)(u.z >> 16));
        a6 += bf2f((u16)(u.w & 0xffffu));
        a7 += bf2f((u16)(u.w >> 16));
    }
#pragma unroll
    for (int o = 16; o <= 32; o <<= 1) {
        a0 += __shfl_xor(a0, o); a1 += __shfl_xor(a1, o);
        a2 += __shfl_xor(a2, o); a3 += __shfl_xor(a3, o);
        a4 += __shfl_xor(a4, o); a5 += __shfl_xor(a5, o);
        a6 += __shfl_xor(a6, o); a7 += __shfl_xor(a7, o);
    }
    if (stream == 0) {
        float sc = inv_deg[wave];
        uint4 p;
        p.x = (u32)f2bf(a0 * sc) | ((u32)f2bf(a1 * sc) << 16);
        p.y = (u32)f2bf(a2 * sc) | ((u32)f2bf(a3 * sc) << 16);
        p.z = (u32)f2bf(a4 * sc) | ((u32)f2bf(a5 * sc) << 16);
        p.w = (u32)f2bf(a6 * sc) | ((u32)f2bf(a7 * sc) << 16);
        *(uint4*)(agb + (size_t)wave * DD + li * 8) = p;
    }
}

// ---------------- MFMA fused SAGEConv layer ----------------

__global__ __launch_bounds__(256) void k_gemm(const float* __restrict__ h_in,
                                              const u16* __restrict__ hb,
                                              const u16* __restrict__ agb,
                                              const u16* __restrict__ wpk,
                                              const float* __restrict__ bias,
                                              const float* __restrict__ gmm,
                                              const float* __restrict__ bet,
                                              float* __restrict__ h_out,
                                              u16* __restrict__ hb_out,
                                              float* __restrict__ emb_out,
                                              int do_ln) {
    __shared__ u16 A[64 * LDA];
    int t = threadIdx.x;
    int b0 = blockIdx.x * 64;

    // stage A: h half (cols 0-127) and agg half (cols 128-255), 16B chunks
#pragma unroll
    for (int j = 0; j < 4; ++j) {
        int idx = t + 256 * j;       // 1024 chunks: 64 rows x 16
        int r = idx >> 4;
        int c = idx & 15;
        int node = b0 + r;
        uint4 v = make_uint4(0, 0, 0, 0), w = make_uint4(0, 0, 0, 0);
        if (node < NN) {
            v = *(const uint4*)(hb + (size_t)node * DD + c * 8);
            w = *(const uint4*)(agb + (size_t)node * DD + c * 8);
        }
        *(uint4*)&A[r * LDA + c * 8] = v;
        *(uint4*)&A[r * LDA + 128 + c * 8] = w;
    }
    __syncthreads();

    int wv = t >> 6, lane = t & 63;
    int m = lane & 15, q = lane >> 4;

    f32x4 acc[8];
#pragma unroll
    for (int nt = 0; nt < 8; ++nt) acc[nt] = (f32x4)(0.f);

    const u16* Arow = &A[(wv * 16 + m) * LDA + q * 8];
    const short8* wp = (const short8*)wpk;
#pragma unroll
    for (int ks = 0; ks < 8; ++ks) {
        short8 af = *(const short8*)(Arow + ks * 32);
        const short8* bp = wp + (ks * 8) * 64 + lane;
#pragma unroll
        for (int nt = 0; nt < 8; ++nt) {
            short8 bf = bp[nt * 64];
            acc[nt] = __builtin_amdgcn_mfma_f32_16x16x32_bf16(af, bf, acc[nt], 0, 0, 0);
        }
    }

    float bcol[8], gcol[8], ecol[8];
#pragma unroll
    for (int nt = 0; nt < 8; ++nt) {
        bcol[nt] = bias[nt * 16 + m];
        if (do_ln) { gcol[nt] = gmm[nt * 16 + m]; ecol[nt] = bet[nt * 16 + m]; }
    }

#pragma unroll
    for (int j = 0; j < 4; ++j) {
        int node = b0 + wv * 16 + q * 4 + j;
        bool ok = node < NN;
        const float* hr = h_in + (size_t)node * DD;
        float v[8];
        float s = 0.f, qq = 0.f;
#pragma unroll
        for (int nt = 0; nt < 8; ++nt) {
            float x = acc[nt][j] + bcol[nt];
            if (ok) x += hr[nt * 16 + m];        // fp32 residual
            if (do_ln) {
                x = fmaxf(x, 0.f);
                s += x; qq += x * x;
            }
            v[nt] = x;
        }
        if (do_ln) {
#pragma unroll
            for (int o = 1; o < 16; o <<= 1) {
                s += __shfl_xor(s, o);
                qq += __shfl_xor(qq, o);
            }
            float mu = s * (1.0f / 128.0f);
            float var = fmaxf(qq * (1.0f / 128.0f) - mu * mu, 0.f);
            float rs = rsqrtf(var + 1e-5f);
#pragma unroll
            for (int nt = 0; nt < 8; ++nt)
                v[nt] = gcol[nt] * (v[nt] - mu) * rs + ecol[nt];
        }
        if (ok) {
            float* orow = h_out + (size_t)node * DD;
#pragma unroll
            for (int nt = 0; nt < 8; ++nt) orow[nt * 16 + m] = v[nt];
            if (hb_out) {
                u16* brow = hb_out + (size_t)node * DD;
#pragma unroll
                for (int nt = 0; nt < 8; ++nt) brow[nt * 16 + m] = f2bf(v[nt]);
            }
            if (emb_out) {
                float* erow = emb_out + (size_t)node * DD;
#pragma unroll
                for (int nt = 0; nt < 8; ++nt) erow[nt * 16 + m] = v[nt];
            }
        }
    }
}

// ---------------- output head: logits = h @ Wout + bout (fp32 vector) ----------------

__device__ __forceinline__ void stage_tile(const float* __restrict__ g, int b0,
                                           float* __restrict__ tile, int t) {
#pragma unroll
    for (int j = 0; j < 8; ++j) {
        int idx = t + 256 * j;
        int r = idx >> 5;
        int c = idx & 31;
        int node = b0 + r;
        float4 f = make_float4(0.f, 0.f, 0.f, 0.f);
        if (node < NN) f = *(const float4*)(g + (size_t)node * DD + c * 4);
        *(float4*)&tile[r * DD + c * 4] = f;
    }
}

__global__ __launch_bounds__(256) void k_logits(const float* __restrict__ h,
                                                const float* __restrict__ Wo,
                                                const float* __restrict__ bo,
                                                float* __restrict__ out) {
    __shared__ float tile[64 * DD];
    int t = threadIdx.x;
    int b0 = blockIdx.x * 64;
    int cg = t & 15;
    int ng = t >> 4;
    stage_tile(h, b0, tile, t);
    __syncthreads();
    float acc[4][4];
#pragma unroll
    for (int i = 0; i < 4; ++i)
#pragma unroll
        for (int j = 0; j < 4; ++j) acc[i][j] = 0.f;
    for (int k = 0; k < DD; k += 4) {
        float4 w0 = *(const float4*)(Wo + (k + 0) * CC + cg * 4);
        float4 w1 = *(const float4*)(Wo + (k + 1) * CC + cg * 4);
        float4 w2 = *(const float4*)(Wo + (k + 2) * CC + cg * 4);
        float4 w3 = *(const float4*)(Wo + (k + 3) * CC + cg * 4);
#pragma unroll
        for (int i = 0; i < 4; ++i) {
            float4 hv = *(const float4*)&tile[(ng * 4 + i) * DD + k];
            acc[i][0] = fmaf(hv.x, w0.x, fmaf(hv.y, w1.x, fmaf(hv.z, w2.x, fmaf(hv.w, w3.x, acc[i][0]))));
            acc[i][1] = fmaf(hv.x, w0.y, fmaf(hv.y, w1.y, fmaf(hv.z, w2.y, fmaf(hv.w, w3.y, acc[i][1]))));
            acc[i][2] = fmaf(hv.x, w0.z, fmaf(hv.y, w1.z, fmaf(hv.z, w2.z, fmaf(hv.w, w3.z, acc[i][2]))));
            acc[i][3] = fmaf(hv.x, w0.w, fmaf(hv.y, w1.w, fmaf(hv.z, w2.w, fmaf(hv.w, w3.w, acc[i][3]))));
        }
    }
    float4 b4 = *(const float4*)(bo + cg * 4);
#pragma unroll
    for (int i = 0; i < 4; ++i) {
        int node = b0 + ng * 4 + i;
        if (node < NN) {
            *(float4*)(out + (size_t)node * CC + cg * 4) =
                make_float4(acc[i][0] + b4.x, acc[i][1] + b4.y,
                            acc[i][2] + b4.z, acc[i][3] + b4.w);
        }
    }
}

// ---------------- launch ----------------

extern "C" void kernel_launch(void* const* d_in, const int* in_sizes, int n_in,
                              void* d_out, int out_size, void* d_ws, size_t ws_size,
                              hipStream_t stream) {
    const float* x  = (const float*)d_in[0];
    const int* src  = (const int*)d_in[1];
    const int* dst  = (const int*)d_in[2];
    const float* Ws = (const float*)d_in[3];
    const float* Wn = (const float*)d_in[4];
    const float* bc = (const float*)d_in[5];
    const float* gm = (const float*)d_in[6];
    const float* bt = (const float*)d_in[7];
    const float* Wo = (const float*)d_in[8];
    const float* bo = (const float*)d_in[9];
    float* out = (float*)d_out;   // fp32: logits [NN*CC] then embedding [NN*DD]

    char* p = (char*)d_ws;
    auto alloc = [&](size_t bytes) { void* r = (void*)p; p += (bytes + 255) & ~(size_t)255; return r; };
    float* h0    = (float*)alloc((size_t)NN * DD * 4);
    float* h1    = (float*)alloc((size_t)NN * DD * 4);
    u16* xb      = (u16*)alloc((size_t)NN * DD * 2);
    u16* hb0     = (u16*)alloc((size_t)NN * DD * 2);
    u16* hb1     = (u16*)alloc((size_t)NN * DD * 2);
    u16* agb     = (u16*)alloc((size_t)NN * DD * 2);
    u16* wpk     = (u16*)alloc((size_t)3 * 4096 * 8 * 2);
    float* invd  = (float*)alloc(NN * 4);
    int* deg     = (int*)alloc(NN * 4);
    int* row_off = (int*)alloc((NN + 1) * 4);
    int* cursor  = (int*)alloc(NN * 4);
    int* bsum    = (int*)alloc(NBLK * 4);
    int* csr     = (int*)alloc(EE * 4);

    hipMemsetAsync(deg, 0, NN * 4, stream);
    hipMemsetAsync(cursor, 0, NN * 4, stream);

    k_degree<<<(EE + 255) / 256, 256, 0, stream>>>(dst, deg);
    k_bsum<<<NBLK, SCAN_B, 0, stream>>>(deg, bsum);
    k_bscan<<<1, 128, 0, stream>>>(bsum, row_off);
    k_cscan<<<NBLK, SCAN_B, 0, stream>>>(deg, bsum, row_off, invd);
    k_fill<<<(EE + 255) / 256, 256, 0, stream>>>(src, dst, row_off, cursor, csr);
    k_x2bf<<<(NN * DD / 4 + 255) / 256, 256, 0, stream>>>(x, xb);
    k_wpack<<<(3 * 4096 + 255) / 256, 256, 0, stream>>>(Ws, Wn, wpk);

    const float* hin = x;
    const u16* hbin = xb;
    float* houts[3] = {h0, h1, h0};
    u16* hbouts[3] = {hb0, hb1, (u16*)nullptr};
    for (int l = 0; l < 3; ++l) {
        k_agg<<<(NN + 3) / 4, 256, 0, stream>>>(hbin, row_off, csr, invd, agb);
        k_gemm<<<(NN + 63) / 64, 256, 0, stream>>>(
            hin, hbin, agb, wpk + (size_t)l * 4096 * 8,
            bc + l * DD,
            (l < 2) ? gm + l * DD : (const float*)nullptr,
            (l < 2) ? bt + l * DD : (const float*)nullptr,
            houts[l], hbouts[l],
            (l == 2) ? out + (size_t)NN * CC : (float*)nullptr,
            (l < 2) ? 1 : 0);
        hin = houts[l];
        hbin = hbouts[l];
    }
    k_logits<<<(NN + 63) / 64, 256, 0, stream>>>(h0, Wo, bo, out);
}